// Round 4
// baseline (849.344 us; speedup 1.0000x reference)
//
#include <hip/hip_runtime.h>
#include <stdint.h>

#define NV 163842
#define EPSV 1e-5f

using short8 = __attribute__((ext_vector_type(8))) short;   // 8 bf16 (4 VGPRs)
using f32x4  = __attribute__((ext_vector_type(4))) float;   // MFMA acc

static __device__ __forceinline__ unsigned short f2bf(float f) {
    union { float f; unsigned int i; } v; v.f = f;
    return (unsigned short)((v.i + 0x7FFFu + ((v.i >> 16) & 1u)) >> 16);  // RNE
}
static __device__ __forceinline__ void bf2x(unsigned int w, float& a, float& b) {
    union { unsigned int i; float f; } lo, hi;
    lo.i = w << 16; hi.i = w & 0xFFFF0000u;
    a = lo.f; b = hi.f;
}
// pack two fp32 -> bf16x2 with round-half-up (+0x8000) and v_perm byte select
static __device__ __forceinline__ unsigned int pack2(float a, float b) {
    union { float f; unsigned int i; } ua, ub; ua.f = a; ub.f = b;
    return __builtin_amdgcn_perm(ub.i + 0x8000u, ua.i + 0x8000u, 0x07060302);
}

// ---- zero the stats accumulator (ws re-poisoned every call) ----
__global__ __launch_bounds__(256) void k_zero(float* __restrict__ ACC) {
    ACC[threadIdx.x] = 0.f;
    ACC[256 + threadIdx.x] = 0.f;
}

// ---- cast x fp32->bf16 into C cols [0,64); accumulate per-channel sum/sumsq ----
__global__ __launch_bounds__(256) void k_cast(const float* __restrict__ x,
                                              unsigned short* __restrict__ C,
                                              float* __restrict__ ACC) {
    const int t = threadIdx.x;
    const int wv = t >> 6, lane = t & 63;
    const int v = blockIdx.x * 64 + (t >> 2);
    const int c0 = (t & 3) * 16;
    float f[16];
    const bool valid = v < NV;
    if (valid) {
        const float4* p = (const float4*)(x + (size_t)v * 64 + c0);
#pragma unroll
        for (int i = 0; i < 4; ++i) {
            float4 q = p[i];
            f[i * 4 + 0] = q.x; f[i * 4 + 1] = q.y; f[i * 4 + 2] = q.z; f[i * 4 + 3] = q.w;
        }
        unsigned int o[8];
#pragma unroll
        for (int i = 0; i < 8; ++i)
            o[i] = ((unsigned int)f2bf(f[2 * i])) | (((unsigned int)f2bf(f[2 * i + 1])) << 16);
        uint4* dst = (uint4*)(C + (size_t)v * 256 + c0);
        dst[0] = uint4{o[0], o[1], o[2], o[3]};
        dst[1] = uint4{o[4], o[5], o[6], o[7]};
    } else {
#pragma unroll
        for (int i = 0; i < 16; ++i) f[i] = 0.f;
    }
    float s[16], s2[16];
#pragma unroll
    for (int i = 0; i < 16; ++i) { s[i] = f[i]; s2[i] = f[i] * f[i]; }
#pragma unroll
    for (int mask = 4; mask <= 32; mask <<= 1) {
#pragma unroll
        for (int i = 0; i < 16; ++i) {
            s[i]  += __shfl_xor(s[i],  mask);
            s2[i] += __shfl_xor(s2[i], mask);
        }
    }
    __shared__ float red[4 * 128];
    if ((lane >> 2) == 0) {
        int cb = (lane & 3) * 16;
#pragma unroll
        for (int i = 0; i < 16; ++i) {
            red[wv * 128 + cb + i]      = s[i];
            red[wv * 128 + 64 + cb + i] = s2[i];
        }
    }
    __syncthreads();
    if (t < 128) {
        float v4 = red[t] + red[128 + t] + red[256 + t] + red[384 + t];
        int c = t & 63, which = t >> 6;
        atomicAdd(&ACC[which * 256 + c], v4);
    }
}

// ---- transpose all four W [7cin,64] fp32 -> WT [64,7cin] bf16, one launch ----
__global__ __launch_bounds__(256) void k_wt_all(const float* __restrict__ W1,
                                                const float* __restrict__ W2,
                                                const float* __restrict__ W3,
                                                const float* __restrict__ W4,
                                                unsigned short* __restrict__ WT) {
    int j = blockIdx.x * 256 + threadIdx.x;
    if (j >= 286720) return;
    const float* W; int jj, K7;
    if (j < 28672)       { W = W1; jj = j;          K7 = 448;  }
    else if (j < 86016)  { W = W2; jj = j - 28672;  K7 = 896;  }
    else if (j < 172032) { W = W3; jj = j - 86016;  K7 = 1344; }
    else                 { W = W4; jj = j - 172032; K7 = 1792; }
    int n = jj / K7, k = jj - n * K7;
    WT[j] = f2bf(W[(size_t)k * 64 + n]);
}

// ---- per-layer BN+LeakyReLU applied ONCE per vertex (not per gathered copy) ----
// reads raw concat C[:, :CIN] (stride 256), writes normalized CN[:, :CIN] (stride CIN)
template<int CIN>
__global__ __launch_bounds__(256) void k_norm(const unsigned short* __restrict__ C,
                                              const float* __restrict__ ACC,
                                              const float* __restrict__ g,
                                              const float* __restrict__ b,
                                              unsigned short* __restrict__ CN) {
    __shared__ float ssc[256], ssh[256];
    const int t = threadIdx.x;
    if (t < CIN) {
        float s = ACC[t], s2 = ACC[256 + t];
        float mu = s * (1.0f / NV);
        float var = fmaf(-mu, mu, s2 * (1.0f / NV));
        float sc = g[t] * rsqrtf(var + EPSV);
        ssc[t] = sc;
        ssh[t] = b[t] - mu * sc;
    }
    __syncthreads();
    constexpr int C8 = CIN / 8;
    const int total = NV * C8;
    for (int idx = blockIdx.x * 256 + t; idx < total; idx += gridDim.x * 256) {
        int v = idx / C8;
        int c8 = idx - v * C8;
        int ch = c8 * 8;
        uint4 u = *(const uint4*)(C + (size_t)v * 256 + ch);
        unsigned int in[4] = {u.x, u.y, u.z, u.w}, o[4];
#pragma unroll
        for (int j = 0; j < 4; ++j) {
            float lo, hi; bf2x(in[j], lo, hi);
            float y0 = fmaf(lo, ssc[ch + 2 * j],     ssh[ch + 2 * j]);
            float y1 = fmaf(hi, ssc[ch + 2 * j + 1], ssh[ch + 2 * j + 1]);
            y0 = y0 > 0.f ? y0 : 0.2f * y0;
            y1 = y1 > 0.f ? y1 : 0.2f * y1;
            o[j] = pack2(y0, y1);
        }
        *(uint4*)(CN + (size_t)v * CIN + ch) = uint4{o[0], o[1], o[2], o[3]};
    }
}

// ---- gathered GEMM, all-register: A and B fragments loaded straight from global
//      in MFMA lane layout (lane m=row, quad=k-group). No LDS tiles, no barriers
//      in the K-loop -> each wave pipelines its own gather latency independently. ----
template<int CIN, int GRP, bool FINAL>
__global__ __launch_bounds__(256) void k_gg(const unsigned short* __restrict__ CN,
                                            const int* __restrict__ neigh,
                                            const unsigned short* __restrict__ WT,
                                            const float* __restrict__ wb,
                                            float* __restrict__ ACC,
                                            unsigned short* __restrict__ Cout,
                                            float* __restrict__ Fout) {
    constexpr int KB = CIN / 64;      // 64-wide K-chunks per neighbor
    constexpr int K7 = 7 * CIN;       // WT row stride (shorts)

    __shared__ int sIdx[896];
    __shared__ float red[1024];

    const int t = threadIdx.x;
    const int v0 = blockIdx.x * 128;
    const int wv = t >> 6, lane = t & 63;
    const int m = lane & 15, quad = lane >> 4;
    const int koff = quad * 8;

    for (int q = t; q < 896; q += 256) {
        int gi = v0 * 7 + q;
        sIdx[q] = (gi < NV * 7) ? neigh[gi] : 0;
    }

    f32x4 acc[2][4];
#pragma unroll
    for (int i = 0; i < 2; ++i)
#pragma unroll
        for (int j = 0; j < 4; ++j) acc[i][j] = f32x4{0.f, 0.f, 0.f, 0.f};

    __syncthreads();   // sIdx ready

    const int row0 = (wv * 32 + m) * 7;        // this lane's M-row (tile 0) index base
    const int row1 = (wv * 32 + 16 + m) * 7;   // M-row (tile 1)

    for (int r = 0; r < 7; ++r) {
        const unsigned short* a0 = CN + (size_t)sIdx[row0 + r] * CIN + koff;
        const unsigned short* a1 = CN + (size_t)sIdx[row1 + r] * CIN + koff;
#pragma unroll
        for (int kb = 0; kb < KB; ++kb) {
            const int c = r * KB + kb;
            short8 af[2][2];
            af[0][0] = *(const short8*)(a0 + kb * 64);
            af[0][1] = *(const short8*)(a0 + kb * 64 + 32);
            af[1][0] = *(const short8*)(a1 + kb * 64);
            af[1][1] = *(const short8*)(a1 + kb * 64 + 32);
            short8 bfr[4][2];
#pragma unroll
            for (int ct = 0; ct < 4; ++ct) {
                const unsigned short* wp = WT + (size_t)(ct * 16 + m) * K7 + c * 64 + koff;
                bfr[ct][0] = *(const short8*)(wp);
                bfr[ct][1] = *(const short8*)(wp + 32);
            }
            __builtin_amdgcn_s_setprio(1);
#pragma unroll
            for (int s = 0; s < 2; ++s)
#pragma unroll
                for (int ct = 0; ct < 4; ++ct) {
                    acc[0][ct] = __builtin_amdgcn_mfma_f32_16x16x32_bf16(af[0][s], bfr[ct][s], acc[0][ct], 0, 0, 0);
                    acc[1][ct] = __builtin_amdgcn_mfma_f32_16x16x32_bf16(af[1][s], bfr[ct][s], acc[1][ct], 0, 0, 0);
                }
            __builtin_amdgcn_s_setprio(0);
        }
    }

    // epilogue: bias, write raw group, per-channel stats for the produced 64-col group
    float bsum[4]  = {0.f, 0.f, 0.f, 0.f};
    float b2sum[4] = {0.f, 0.f, 0.f, 0.f};
#pragma unroll
    for (int mt = 0; mt < 2; ++mt) {
#pragma unroll
        for (int ct = 0; ct < 4; ++ct) {
            int col = ct * 16 + m;
            float bv = wb[col];
#pragma unroll
            for (int j = 0; j < 4; ++j) {
                int vr = v0 + wv * 32 + mt * 16 + quad * 4 + j;
                float val = acc[mt][ct][j] + bv;
                if (vr < NV) {
                    if (FINAL) {
                        Fout[(size_t)vr * 64 + col] = val;
                    } else {
                        Cout[(size_t)vr * 256 + GRP * 64 + col] = f2bf(val);
                        bsum[ct] += val; b2sum[ct] += val * val;
                    }
                }
            }
        }
    }
    if (!FINAL) {
#pragma unroll
        for (int ct = 0; ct < 4; ++ct) {   // reduce over quads (rows within wave)
            bsum[ct]  += __shfl_xor(bsum[ct], 16);
            bsum[ct]  += __shfl_xor(bsum[ct], 32);
            b2sum[ct] += __shfl_xor(b2sum[ct], 16);
            b2sum[ct] += __shfl_xor(b2sum[ct], 32);
        }
        if (quad == 0) {
#pragma unroll
            for (int ct = 0; ct < 4; ++ct) {
                red[wv * 128 + ct * 16 + m]       = bsum[ct];
                red[512 + wv * 128 + ct * 16 + m] = b2sum[ct];
            }
        }
        __syncthreads();
        if (t < 128) {
            int c = t & 63, which = t >> 6;
            float v = red[which * 512 + c] + red[which * 512 + 128 + c] +
                      red[which * 512 + 256 + c] + red[which * 512 + 384 + c];
            atomicAdd(&ACC[which * 256 + GRP * 64 + c], v);
        }
    }
}

extern "C" void kernel_launch(void* const* d_in, const int* in_sizes, int n_in,
                              void* d_out, int out_size, void* d_ws, size_t ws_size,
                              hipStream_t stream) {
    const float* x     = (const float*)d_in[0];
    const int*   neigh = (const int*)d_in[1];
    const float* G[4]  = {(const float*)d_in[2],  (const float*)d_in[6],
                          (const float*)d_in[10], (const float*)d_in[14]};
    const float* B[4]  = {(const float*)d_in[3],  (const float*)d_in[7],
                          (const float*)d_in[11], (const float*)d_in[15]};
    const float* W[4]  = {(const float*)d_in[4],  (const float*)d_in[8],
                          (const float*)d_in[12], (const float*)d_in[16]};
    const float* WB[4] = {(const float*)d_in[5],  (const float*)d_in[9],
                          (const float*)d_in[13], (const float*)d_in[17]};
    float* out = (float*)d_out;

    char* ws = (char*)d_ws;
    size_t off = 0;
    unsigned short* C  = (unsigned short*)(ws + off); off += (size_t)NV * 256 * 2;  // raw concat x|x1|x2|x3 (bf16)
    unsigned short* CN = (unsigned short*)(ws + off); off += (size_t)NV * 256 * 2;  // per-layer normalized rows
    unsigned short* WT = (unsigned short*)(ws + off); off += (size_t)286720 * 2;    // all 4 transposed W
    float* ACC         = (float*)(ws + off);          off += 512 * 4;               // sum[256], sumsq[256]

    k_zero<<<1, 256, 0, stream>>>(ACC);
    k_cast<<<(NV + 63) / 64, 256, 0, stream>>>(x, C, ACC);
    k_wt_all<<<(286720 + 255) / 256, 256, 0, stream>>>(W[0], W[1], W[2], W[3], WT);

    const int GG = (NV + 127) / 128;
    const int NB = 2048;   // grid-stride cap for norm passes

    k_norm< 64><<<NB, 256, 0, stream>>>(C, ACC, G[0], B[0], CN);
    k_gg< 64, 1, false><<<GG, 256, 0, stream>>>(CN, neigh, WT,          WB[0], ACC, C, nullptr);
    k_norm<128><<<NB, 256, 0, stream>>>(C, ACC, G[1], B[1], CN);
    k_gg<128, 2, false><<<GG, 256, 0, stream>>>(CN, neigh, WT + 28672,  WB[1], ACC, C, nullptr);
    k_norm<192><<<NB, 256, 0, stream>>>(C, ACC, G[2], B[2], CN);
    k_gg<192, 3, false><<<GG, 256, 0, stream>>>(CN, neigh, WT + 86016,  WB[2], ACC, C, nullptr);
    k_norm<256><<<NB, 256, 0, stream>>>(C, ACC, G[3], B[3], CN);
    k_gg<256, 0, true ><<<GG, 256, 0, stream>>>(CN, neigh, WT + 172032, WB[3], ACC, nullptr, out);
}

// Round 5
// 723.102 us; speedup vs baseline: 1.1746x; 1.1746x over previous
//
#include <hip/hip_runtime.h>
#include <stdint.h>

#define NV 163842
#define EPSV 1e-5f

using short8 = __attribute__((ext_vector_type(8))) short;   // 8 bf16 (4 VGPRs)
using f32x4  = __attribute__((ext_vector_type(4))) float;   // MFMA acc

static __device__ __forceinline__ unsigned short f2bf(float f) {
    union { float f; unsigned int i; } v; v.f = f;
    return (unsigned short)((v.i + 0x7FFFu + ((v.i >> 16) & 1u)) >> 16);  // RNE
}
static __device__ __forceinline__ void bf2x(unsigned int w, float& a, float& b) {
    union { unsigned int i; float f; } lo, hi;
    lo.i = w << 16; hi.i = w & 0xFFFF0000u;
    a = lo.f; b = hi.f;
}
// pack two fp32 -> bf16x2 with round-half-up (+0x8000) and v_perm byte select
static __device__ __forceinline__ unsigned int pack2(float a, float b) {
    union { float f; unsigned int i; } ua, ub; ua.f = a; ub.f = b;
    return __builtin_amdgcn_perm(ub.i + 0x8000u, ua.i + 0x8000u, 0x07060302);
}

// direct global->LDS, 16B per lane; LDS dest is wave-uniform base + lane*16
static __device__ __forceinline__ void gl_lds16(const unsigned short* g, unsigned short* l) {
    __builtin_amdgcn_global_load_lds((__attribute__((address_space(1))) void*)g,
                                     (__attribute__((address_space(3))) void*)l, 16, 0, 0);
}

// ---- zero the stats accumulator (ws re-poisoned every call) ----
__global__ __launch_bounds__(256) void k_zero(float* __restrict__ ACC) {
    ACC[threadIdx.x] = 0.f;
    ACC[256 + threadIdx.x] = 0.f;
}

// ---- cast x fp32->bf16 into C cols [0,64); accumulate per-channel sum/sumsq ----
__global__ __launch_bounds__(256) void k_cast(const float* __restrict__ x,
                                              unsigned short* __restrict__ C,
                                              float* __restrict__ ACC) {
    const int t = threadIdx.x;
    const int wv = t >> 6, lane = t & 63;
    const int v = blockIdx.x * 64 + (t >> 2);
    const int c0 = (t & 3) * 16;
    float f[16];
    const bool valid = v < NV;
    if (valid) {
        const float4* p = (const float4*)(x + (size_t)v * 64 + c0);
#pragma unroll
        for (int i = 0; i < 4; ++i) {
            float4 q = p[i];
            f[i * 4 + 0] = q.x; f[i * 4 + 1] = q.y; f[i * 4 + 2] = q.z; f[i * 4 + 3] = q.w;
        }
        unsigned int o[8];
#pragma unroll
        for (int i = 0; i < 8; ++i)
            o[i] = ((unsigned int)f2bf(f[2 * i])) | (((unsigned int)f2bf(f[2 * i + 1])) << 16);
        uint4* dst = (uint4*)(C + (size_t)v * 256 + c0);
        dst[0] = uint4{o[0], o[1], o[2], o[3]};
        dst[1] = uint4{o[4], o[5], o[6], o[7]};
    } else {
#pragma unroll
        for (int i = 0; i < 16; ++i) f[i] = 0.f;
    }
    float s[16], s2[16];
#pragma unroll
    for (int i = 0; i < 16; ++i) { s[i] = f[i]; s2[i] = f[i] * f[i]; }
#pragma unroll
    for (int mask = 4; mask <= 32; mask <<= 1) {
#pragma unroll
        for (int i = 0; i < 16; ++i) {
            s[i]  += __shfl_xor(s[i],  mask);
            s2[i] += __shfl_xor(s2[i], mask);
        }
    }
    __shared__ float red[4 * 128];
    if ((lane >> 2) == 0) {
        int cb = (lane & 3) * 16;
#pragma unroll
        for (int i = 0; i < 16; ++i) {
            red[wv * 128 + cb + i]      = s[i];
            red[wv * 128 + 64 + cb + i] = s2[i];
        }
    }
    __syncthreads();
    if (t < 128) {
        float v4 = red[t] + red[128 + t] + red[256 + t] + red[384 + t];
        int c = t & 63, which = t >> 6;
        atomicAdd(&ACC[which * 256 + c], v4);
    }
}

// ---- transpose all four W [7cin,64] fp32 -> WT [64,7cin] bf16, one launch ----
__global__ __launch_bounds__(256) void k_wt_all(const float* __restrict__ W1,
                                                const float* __restrict__ W2,
                                                const float* __restrict__ W3,
                                                const float* __restrict__ W4,
                                                unsigned short* __restrict__ WT) {
    int j = blockIdx.x * 256 + threadIdx.x;
    if (j >= 286720) return;
    const float* W; int jj, K7;
    if (j < 28672)       { W = W1; jj = j;          K7 = 448;  }
    else if (j < 86016)  { W = W2; jj = j - 28672;  K7 = 896;  }
    else if (j < 172032) { W = W3; jj = j - 86016;  K7 = 1344; }
    else                 { W = W4; jj = j - 172032; K7 = 1792; }
    int n = jj / K7, k = jj - n * K7;
    WT[j] = f2bf(W[(size_t)k * 64 + n]);
}

// ---- per-layer BN+LeakyReLU applied ONCE per vertex (not per gathered copy) ----
// reads raw concat C[:, :CIN] (stride 256), writes normalized CN[:, :CIN] (stride CIN)
template<int CIN>
__global__ __launch_bounds__(256) void k_norm(const unsigned short* __restrict__ C,
                                              const float* __restrict__ ACC,
                                              const float* __restrict__ g,
                                              const float* __restrict__ b,
                                              unsigned short* __restrict__ CN) {
    __shared__ float ssc[256], ssh[256];
    const int t = threadIdx.x;
    if (t < CIN) {
        float s = ACC[t], s2 = ACC[256 + t];
        float mu = s * (1.0f / NV);
        float var = fmaf(-mu, mu, s2 * (1.0f / NV));
        float sc = g[t] * rsqrtf(var + EPSV);
        ssc[t] = sc;
        ssh[t] = b[t] - mu * sc;
    }
    __syncthreads();
    constexpr int C8 = CIN / 8;
    const int total = NV * C8;
    for (int idx = blockIdx.x * 256 + t; idx < total; idx += gridDim.x * 256) {
        int v = idx / C8;
        int c8 = idx - v * C8;
        int ch = c8 * 8;
        uint4 u = *(const uint4*)(C + (size_t)v * 256 + ch);
        unsigned int in[4] = {u.x, u.y, u.z, u.w}, o[4];
#pragma unroll
        for (int j = 0; j < 4; ++j) {
            float lo, hi; bf2x(in[j], lo, hi);
            float y0 = fmaf(lo, ssc[ch + 2 * j],     ssh[ch + 2 * j]);
            float y1 = fmaf(hi, ssc[ch + 2 * j + 1], ssh[ch + 2 * j + 1]);
            y0 = y0 > 0.f ? y0 : 0.2f * y0;
            y1 = y1 > 0.f ? y1 : 0.2f * y1;
            o[j] = pack2(y0, y1);
        }
        *(uint4*)(CN + (size_t)v * CIN + ch) = uint4{o[0], o[1], o[2], o[3]};
    }
}

// ---- gathered GEMM, barrier-free K-loop:
//      A (gathered rows) -> LDS via global_load_lds, WAVE-PRIVATE regions only
//      B (weights)       -> per-lane registers, double-buffered (L2-resident)
//      per-wave counted s_waitcnt vmcnt(12): chunk c+1's 12 loads stay in flight
//      while chunk c computes. No __syncthreads in the K-loop at all. ----
template<int CIN, int GRP, bool FINAL>
__global__ __launch_bounds__(256) void k_gg(const unsigned short* __restrict__ CN,
                                            const int* __restrict__ neigh,
                                            const unsigned short* __restrict__ WT,
                                            const float* __restrict__ wb,
                                            float* __restrict__ ACC,
                                            unsigned short* __restrict__ Cout,
                                            float* __restrict__ Fout) {
    constexpr int KB = CIN / 64;      // 64-wide K-chunks per neighbor
    constexpr int NC = 7 * KB;        // total K chunks
    constexpr int K7 = 7 * CIN;       // WT row stride (shorts)

    __shared__ int sIdx[896];
    __shared__ unsigned short sA[2][128 * 64];   // 2-deep ring, wave-private 32-row slices

    const int t = threadIdx.x;
    const int v0 = blockIdx.x * 128;
    const int wv = t >> 6, lane = t & 63;
    const int m = lane & 15, quad = lane >> 4;
    const int rowin = lane >> 3, slot = lane & 7;
    const int sw = ((slot ^ rowin) * 8);      // swizzled source offset within chunk (shorts)

    for (int q = t; q < 896; q += 256) {
        int gi = v0 * 7 + q;
        sIdx[q] = (gi < NV * 7) ? neigh[gi] : 0;
    }

    f32x4 acc[2][4];
#pragma unroll
    for (int i = 0; i < 2; ++i)
#pragma unroll
        for (int j = 0; j < 4; ++j) acc[i][j] = f32x4{0.f, 0.f, 0.f, 0.f};

    __syncthreads();   // sIdx ready (only barrier before the epilogue)

    // issue the 4 A-stage loads for chunk c into ring slot c&1 (wave-private rows)
    auto stageA = [&](int c) {
        int r = c / KB, kb = c - r * KB;
#pragma unroll
        for (int i = 0; i < 4; ++i) {
            int gidx = sIdx[(wv * 32 + i * 8 + rowin) * 7 + r];
            gl_lds16(CN + (size_t)gidx * CIN + kb * 64 + sw, &sA[c & 1][(wv * 32 + i * 8) * 64]);
        }
    };
    // issue the 8 B register loads for chunk c (layout verified in round 4)
    auto loadB = [&](int c, short8 (&b)[4][2]) {
#pragma unroll
        for (int ct = 0; ct < 4; ++ct) {
            const unsigned short* wp = WT + (size_t)(ct * 16 + m) * K7 + c * 64 + quad * 8;
            b[ct][0] = *(const short8*)(wp);
            b[ct][1] = *(const short8*)(wp + 32);
        }
    };
    // consume chunk c from sA[c&1] + bc; prefetch chunk c+1 into bn + sA[(c+1)&1]
    auto step = [&](int c, short8 (&bc)[4][2], short8 (&bn)[4][2]) {
        if (c + 1 < NC) {
            loadB(c + 1, bn);
            stageA(c + 1);
            asm volatile("s_waitcnt vmcnt(12)" ::: "memory");  // drain chunk c's 12, keep c+1 in flight
        } else {
            asm volatile("s_waitcnt vmcnt(0)" ::: "memory");
        }
        __builtin_amdgcn_sched_barrier(0);
        const unsigned short* sa = &sA[c & 1][0];
        __builtin_amdgcn_s_setprio(1);
#pragma unroll
        for (int s = 0; s < 2; ++s) {
            const int sx = ((s * 4 + quad) ^ (m & 7)) * 8;   // swizzled frag read (shorts)
            short8 af0 = *(const short8*)(sa + (wv * 32 + m) * 64 + sx);
            short8 af1 = *(const short8*)(sa + (wv * 32 + 16 + m) * 64 + sx);
#pragma unroll
            for (int ct = 0; ct < 4; ++ct) {
                acc[0][ct] = __builtin_amdgcn_mfma_f32_16x16x32_bf16(af0, bc[ct][s], acc[0][ct], 0, 0, 0);
                acc[1][ct] = __builtin_amdgcn_mfma_f32_16x16x32_bf16(af1, bc[ct][s], acc[1][ct], 0, 0, 0);
            }
        }
        __builtin_amdgcn_s_setprio(0);
    };

    short8 b0[4][2], b1[4][2];
    loadB(0, b0);
    stageA(0);                     // 12 outstanding
#pragma unroll
    for (int c = 0; c < NC; ++c) {
        if (c & 1) step(c, b1, b0);
        else       step(c, b0, b1);
    }

    __syncthreads();   // all waves done with sA before reuse as reduction scratch

    // epilogue: bias, write raw group, per-channel stats for the produced 64-col group
    float bsum[4]  = {0.f, 0.f, 0.f, 0.f};
    float b2sum[4] = {0.f, 0.f, 0.f, 0.f};
#pragma unroll
    for (int mt = 0; mt < 2; ++mt) {
#pragma unroll
        for (int ct = 0; ct < 4; ++ct) {
            int col = ct * 16 + m;
            float bv = wb[col];
#pragma unroll
            for (int j = 0; j < 4; ++j) {
                int vr = v0 + wv * 32 + mt * 16 + quad * 4 + j;
                float val = acc[mt][ct][j] + bv;
                if (vr < NV) {
                    if (FINAL) {
                        Fout[(size_t)vr * 64 + col] = val;
                    } else {
                        Cout[(size_t)vr * 256 + GRP * 64 + col] = f2bf(val);
                        bsum[ct] += val; b2sum[ct] += val * val;
                    }
                }
            }
        }
    }
    if (!FINAL) {
#pragma unroll
        for (int ct = 0; ct < 4; ++ct) {   // reduce over quads (rows within wave)
            bsum[ct]  += __shfl_xor(bsum[ct], 16);
            bsum[ct]  += __shfl_xor(bsum[ct], 32);
            b2sum[ct] += __shfl_xor(b2sum[ct], 16);
            b2sum[ct] += __shfl_xor(b2sum[ct], 32);
        }
        float* red = (float*)&sA[0][0];   // sA dead after the post-K-loop __syncthreads
        if (quad == 0) {
#pragma unroll
            for (int ct = 0; ct < 4; ++ct) {
                red[wv * 128 + ct * 16 + m]       = bsum[ct];
                red[512 + wv * 128 + ct * 16 + m] = b2sum[ct];
            }
        }
        __syncthreads();
        if (t < 128) {
            int c = t & 63, which = t >> 6;
            float v = red[which * 512 + c] + red[which * 512 + 128 + c] +
                      red[which * 512 + 256 + c] + red[which * 512 + 384 + c];
            atomicAdd(&ACC[which * 256 + GRP * 64 + c], v);
        }
    }
}

extern "C" void kernel_launch(void* const* d_in, const int* in_sizes, int n_in,
                              void* d_out, int out_size, void* d_ws, size_t ws_size,
                              hipStream_t stream) {
    const float* x     = (const float*)d_in[0];
    const int*   neigh = (const int*)d_in[1];
    const float* G[4]  = {(const float*)d_in[2],  (const float*)d_in[6],
                          (const float*)d_in[10], (const float*)d_in[14]};
    const float* B[4]  = {(const float*)d_in[3],  (const float*)d_in[7],
                          (const float*)d_in[11], (const float*)d_in[15]};
    const float* W[4]  = {(const float*)d_in[4],  (const float*)d_in[8],
                          (const float*)d_in[12], (const float*)d_in[16]};
    const float* WB[4] = {(const float*)d_in[5],  (const float*)d_in[9],
                          (const float*)d_in[13], (const float*)d_in[17]};
    float* out = (float*)d_out;

    char* ws = (char*)d_ws;
    size_t off = 0;
    unsigned short* C  = (unsigned short*)(ws + off); off += (size_t)NV * 256 * 2;  // raw concat x|x1|x2|x3 (bf16)
    unsigned short* CN = (unsigned short*)(ws + off); off += (size_t)NV * 256 * 2;  // per-layer normalized rows
    unsigned short* WT = (unsigned short*)(ws + off); off += (size_t)286720 * 2;    // all 4 transposed W
    float* ACC         = (float*)(ws + off);          off += 512 * 4;               // sum[256], sumsq[256]

    k_zero<<<1, 256, 0, stream>>>(ACC);
    k_cast<<<(NV + 63) / 64, 256, 0, stream>>>(x, C, ACC);
    k_wt_all<<<(286720 + 255) / 256, 256, 0, stream>>>(W[0], W[1], W[2], W[3], WT);

    const int GG = (NV + 127) / 128;
    const int NB = 2048;   // grid-stride cap for norm passes

    k_norm< 64><<<NB, 256, 0, stream>>>(C, ACC, G[0], B[0], CN);
    k_gg< 64, 1, false><<<GG, 256, 0, stream>>>(CN, neigh, WT,          WB[0], ACC, C, nullptr);
    k_norm<128><<<NB, 256, 0, stream>>>(C, ACC, G[1], B[1], CN);
    k_gg<128, 2, false><<<GG, 256, 0, stream>>>(CN, neigh, WT + 28672,  WB[1], ACC, C, nullptr);
    k_norm<192><<<NB, 256, 0, stream>>>(C, ACC, G[2], B[2], CN);
    k_gg<192, 3, false><<<GG, 256, 0, stream>>>(CN, neigh, WT + 86016,  WB[2], ACC, C, nullptr);
    k_norm<256><<<NB, 256, 0, stream>>>(C, ACC, G[3], B[3], CN);
    k_gg<256, 0, true ><<<GG, 256, 0, stream>>>(CN, neigh, WT + 172032, WB[3], ACC, nullptr, out);
}

// Round 6
// 676.406 us; speedup vs baseline: 1.2557x; 1.0690x over previous
//
#include <hip/hip_runtime.h>
#include <stdint.h>

#define NV 163842
#define EPSV 1e-5f

using short8 = __attribute__((ext_vector_type(8))) short;   // 8 bf16 (4 VGPRs)
using f32x4  = __attribute__((ext_vector_type(4))) float;   // MFMA acc

static __device__ __forceinline__ unsigned short f2bf(float f) {
    union { float f; unsigned int i; } v; v.f = f;
    return (unsigned short)((v.i + 0x7FFFu + ((v.i >> 16) & 1u)) >> 16);  // RNE
}
static __device__ __forceinline__ void bf2x(unsigned int w, float& a, float& b) {
    union { unsigned int i; float f; } lo, hi;
    lo.i = w << 16; hi.i = w & 0xFFFF0000u;
    a = lo.f; b = hi.f;
}
// pack two fp32 -> bf16x2 with round-half-up (+0x8000) and v_perm byte select
static __device__ __forceinline__ unsigned int pack2(float a, float b) {
    union { float f; unsigned int i; } ua, ub; ua.f = a; ub.f = b;
    return __builtin_amdgcn_perm(ub.i + 0x8000u, ua.i + 0x8000u, 0x07060302);
}

// direct global->LDS, 16B per lane; LDS dest is wave-uniform base + lane*16
static __device__ __forceinline__ void gl_lds16(const unsigned short* g, unsigned short* l) {
    __builtin_amdgcn_global_load_lds((__attribute__((address_space(1))) void*)g,
                                     (__attribute__((address_space(3))) void*)l, 16, 0, 0);
}

// ---- merged: cast x fp32->bf16 into C cols [0,64) + per-channel stats,
//      and transpose all four W -> WT bf16 (blockIdx branch) ----
#define CAST_BLOCKS 2561   /* (NV+63)/64 */
#define WT_BLOCKS   1120   /* 286720/256 */
__global__ __launch_bounds__(256) void k_cast_wt(const float* __restrict__ x,
                                                 unsigned short* __restrict__ C,
                                                 float* __restrict__ ACC,
                                                 const float* __restrict__ W1,
                                                 const float* __restrict__ W2,
                                                 const float* __restrict__ W3,
                                                 const float* __restrict__ W4,
                                                 unsigned short* __restrict__ WT) {
    const int t = threadIdx.x;
    if (blockIdx.x >= CAST_BLOCKS) {   // ---- W transpose part ----
        int j = (blockIdx.x - CAST_BLOCKS) * 256 + t;
        if (j >= 286720) return;
        const float* W; int jj, K7;
        if (j < 28672)       { W = W1; jj = j;          K7 = 448;  }
        else if (j < 86016)  { W = W2; jj = j - 28672;  K7 = 896;  }
        else if (j < 172032) { W = W3; jj = j - 86016;  K7 = 1344; }
        else                 { W = W4; jj = j - 172032; K7 = 1792; }
        int n = jj / K7, k = jj - n * K7;
        WT[j] = f2bf(W[(size_t)k * 64 + n]);
        return;
    }
    // ---- cast + stats part ----
    const int wv = t >> 6, lane = t & 63;
    const int v = blockIdx.x * 64 + (t >> 2);
    const int c0 = (t & 3) * 16;
    float f[16];
    const bool valid = v < NV;
    if (valid) {
        const float4* p = (const float4*)(x + (size_t)v * 64 + c0);
#pragma unroll
        for (int i = 0; i < 4; ++i) {
            float4 q = p[i];
            f[i * 4 + 0] = q.x; f[i * 4 + 1] = q.y; f[i * 4 + 2] = q.z; f[i * 4 + 3] = q.w;
        }
        unsigned int o[8];
#pragma unroll
        for (int i = 0; i < 8; ++i)
            o[i] = ((unsigned int)f2bf(f[2 * i])) | (((unsigned int)f2bf(f[2 * i + 1])) << 16);
        uint4* dst = (uint4*)(C + (size_t)v * 256 + c0);
        dst[0] = uint4{o[0], o[1], o[2], o[3]};
        dst[1] = uint4{o[4], o[5], o[6], o[7]};
    } else {
#pragma unroll
        for (int i = 0; i < 16; ++i) f[i] = 0.f;
    }
    float s[16], s2[16];
#pragma unroll
    for (int i = 0; i < 16; ++i) { s[i] = f[i]; s2[i] = f[i] * f[i]; }
#pragma unroll
    for (int mask = 4; mask <= 32; mask <<= 1) {
#pragma unroll
        for (int i = 0; i < 16; ++i) {
            s[i]  += __shfl_xor(s[i],  mask);
            s2[i] += __shfl_xor(s2[i], mask);
        }
    }
    __shared__ float red[4 * 128];
    if ((lane >> 2) == 0) {
        int cb = (lane & 3) * 16;
#pragma unroll
        for (int i = 0; i < 16; ++i) {
            red[wv * 128 + cb + i]      = s[i];
            red[wv * 128 + 64 + cb + i] = s2[i];
        }
    }
    __syncthreads();
    if (t < 128) {
        float v4 = red[t] + red[128 + t] + red[256 + t] + red[384 + t];
        int c = t & 63, which = t >> 6;
        atomicAdd(&ACC[which * 256 + c], v4);
    }
}

// ---- per-layer BN+LeakyReLU, applied once per vertex, with DATA-ADAPTIVE group
//      skipping: a 64-col group is rewritten only if this layer's (g,b) slice
//      differs from the params the group's CN content currently embodies.
//      (mu/var of old channels never change; equal params -> bit-identical output.)
//      CN is stride-256 so group addresses are layer-invariant. ----
template<int L>   // layer 1..4, CIN = 64*L
__global__ __launch_bounds__(256) void k_norm(const unsigned short* __restrict__ C,
                                              const float* __restrict__ ACC,
                                              const float* __restrict__ G1, const float* __restrict__ B1,
                                              const float* __restrict__ G2, const float* __restrict__ B2,
                                              const float* __restrict__ G3, const float* __restrict__ B3,
                                              const float* __restrict__ G4, const float* __restrict__ B4,
                                              unsigned short* __restrict__ CN) {
    constexpr int CIN = 64 * L;
    __shared__ float ssc[256], ssh[256];
    const int t = threadIdx.x;
    const float* Gs[4] = {G1, G2, G3, G4};
    const float* Bs[4] = {B1, B2, B3, B4};
    if (t < CIN) {
        float s = ACC[t], s2 = ACC[256 + t];
        float mu = s * (1.0f / NV);
        float var = fmaf(-mu, mu, s2 * (1.0f / NV));
        float sc = Gs[L - 1][t] * rsqrtf(var + EPSV);
        ssc[t] = sc;
        ssh[t] = Bs[L - 1][t] - mu * sc;
    }
    __syncthreads();

    // uniform (scalarized) param-chain replay; identical result in every block
    auto differs = [&](const float* ga, const float* ba,
                       const float* gb, const float* bb, int off) -> bool {
        for (int c = 0; c < 64; ++c)
            if (ga[off + c] != gb[off + c] || ba[off + c] != bb[off + c]) return true;
        return false;
    };

    for (int g = 0; g < L; ++g) {
        bool need;
        if (g == L - 1) {
            need = true;                      // new group: first normalization
        } else {
            int effL = g;                     // 0-based layer whose params the group embodies
            for (int l = g + 1; l <= L - 2; ++l)
                if (differs(Gs[l], Bs[l], Gs[effL], Bs[effL], g * 64)) effL = l;
            need = differs(Gs[L - 1], Bs[L - 1], Gs[effL], Bs[effL], g * 64);
        }
        if (!need) continue;
        const int total = NV * 8;             // 8 x (8-channel uint4 chunks) per row
        for (int idx = blockIdx.x * 256 + t; idx < total; idx += gridDim.x * 256) {
            int v = idx >> 3;
            int ch = g * 64 + (idx & 7) * 8;
            uint4 u = *(const uint4*)(C + (size_t)v * 256 + ch);
            unsigned int in[4] = {u.x, u.y, u.z, u.w}, o[4];
#pragma unroll
            for (int j = 0; j < 4; ++j) {
                float lo, hi; bf2x(in[j], lo, hi);
                float y0 = fmaf(lo, ssc[ch + 2 * j],     ssh[ch + 2 * j]);
                float y1 = fmaf(hi, ssc[ch + 2 * j + 1], ssh[ch + 2 * j + 1]);
                y0 = y0 > 0.f ? y0 : 0.2f * y0;
                y1 = y1 > 0.f ? y1 : 0.2f * y1;
                o[j] = pack2(y0, y1);
            }
            *(uint4*)(CN + (size_t)v * 256 + ch) = uint4{o[0], o[1], o[2], o[3]};
        }
    }
}

// ---- gathered GEMM (round-3 verified structure, at the random-fetch roofline):
//      pure-copy gather via global_load_lds, double-buffered LDS, T3 minimal
//      pipeline: STAGE(next) -> compute(cur) -> __syncthreads -> swap. ----
template<int CIN, int GRP, bool FINAL>
__global__ __launch_bounds__(256) void k_gg(const unsigned short* __restrict__ CN,
                                            const int* __restrict__ neigh,
                                            const unsigned short* __restrict__ WT,
                                            const float* __restrict__ wb,
                                            float* __restrict__ ACC,
                                            unsigned short* __restrict__ Cout,
                                            float* __restrict__ Fout) {
    constexpr int KB = CIN / 64;      // K-chunks per neighbor
    constexpr int NC = 7 * KB;        // total 64-wide K chunks
    constexpr int K7 = 7 * CIN;       // WT row stride (shorts)

    __shared__ int sIdx[896];
    __shared__ unsigned short sA[2][128 * 64];   // double-buffered, linear, 128 B rows
    __shared__ unsigned short sW[2][64 * 64];

    const int t = threadIdx.x;
    const int v0 = blockIdx.x * 128;
    const int wv = t >> 6, lane = t & 63;
    const int m = lane & 15, quad = lane >> 4;
    const int rowin = lane >> 3, slot = lane & 7;
    const int sw = ((slot ^ rowin) * 8);      // swizzled source offset within chunk (shorts)

    for (int q = t; q < 896; q += 256) {
        int gi = v0 * 7 + q;
        sIdx[q] = (gi < NV * 7) ? neigh[gi] : 0;
    }

    f32x4 acc[2][4];
#pragma unroll
    for (int i = 0; i < 2; ++i)
#pragma unroll
        for (int j = 0; j < 4; ++j) acc[i][j] = f32x4{0.f, 0.f, 0.f, 0.f};

    __syncthreads();   // sIdx ready

    auto issue_stage = [&](int r, int kb, int c, int b) {
        // A: 4 issues/wave, 8 rows each; CN rows are stride-256 now
#pragma unroll
        for (int i = 0; i < 4; ++i) {
            int gidx = sIdx[(wv * 32 + i * 8 + rowin) * 7 + r];
            gl_lds16(CN + (size_t)gidx * 256 + kb * 64 + sw, &sA[b][(wv * 32 + i * 8) * 64]);
        }
        // W: 2 issues/wave
#pragma unroll
        for (int j = 0; j < 2; ++j) {
            int n = wv * 16 + j * 8 + rowin;
            gl_lds16(WT + (size_t)n * K7 + c * 64 + sw, &sW[b][(wv * 16 + j * 8) * 64]);
        }
    };
    auto compute = [&](int b) {
        __builtin_amdgcn_s_setprio(1);
#pragma unroll
        for (int s = 0; s < 2; ++s) {
            const int sx = ((s * 4 + quad) ^ (m & 7)) * 8;   // swizzled frag read (shorts)
            short8 af0 = *(const short8*)(&sA[b][(wv * 32 + m) * 64 + sx]);
            short8 af1 = *(const short8*)(&sA[b][(wv * 32 + 16 + m) * 64 + sx]);
#pragma unroll
            for (int ct = 0; ct < 4; ++ct) {
                short8 bf = *(const short8*)(&sW[b][(ct * 16 + m) * 64 + sx]);
                acc[0][ct] = __builtin_amdgcn_mfma_f32_16x16x32_bf16(af0, bf, acc[0][ct], 0, 0, 0);
                acc[1][ct] = __builtin_amdgcn_mfma_f32_16x16x32_bf16(af1, bf, acc[1][ct], 0, 0, 0);
            }
        }
        __builtin_amdgcn_s_setprio(0);
    };

    issue_stage(0, 0, 0, 0);
    __syncthreads();

    int r = 0, kb = 0, buf = 0;
    for (int c = 0; c < NC - 1; ++c) {
        int kb1 = kb + 1, r1 = r;
        if (kb1 == KB) { kb1 = 0; r1 = r + 1; }
        issue_stage(r1, kb1, c + 1, buf ^ 1);   // in flight across the compute phase
        compute(buf);
        __syncthreads();                        // drains vmcnt(0): chunk c+1 resident; buf reusable
        r = r1; kb = kb1; buf ^= 1;
    }
    compute(buf);
    __syncthreads();   // before reusing sA as reduction scratch

    // epilogue: bias, write raw group, per-channel stats for the produced 64-col group
    float bsum[4]  = {0.f, 0.f, 0.f, 0.f};
    float b2sum[4] = {0.f, 0.f, 0.f, 0.f};
#pragma unroll
    for (int mt = 0; mt < 2; ++mt) {
#pragma unroll
        for (int ct = 0; ct < 4; ++ct) {
            int col = ct * 16 + m;
            float bv = wb[col];
#pragma unroll
            for (int j = 0; j < 4; ++j) {
                int vr = v0 + wv * 32 + mt * 16 + quad * 4 + j;
                float val = acc[mt][ct][j] + bv;
                if (vr < NV) {
                    if (FINAL) {
                        Fout[(size_t)vr * 64 + col] = val;
                    } else {
                        Cout[(size_t)vr * 256 + GRP * 64 + col] = f2bf(val);
                        bsum[ct] += val; b2sum[ct] += val * val;
                    }
                }
            }
        }
    }
    if (!FINAL) {
#pragma unroll
        for (int ct = 0; ct < 4; ++ct) {   // reduce over quads (rows within wave)
            bsum[ct]  += __shfl_xor(bsum[ct], 16);
            bsum[ct]  += __shfl_xor(bsum[ct], 32);
            b2sum[ct] += __shfl_xor(b2sum[ct], 16);
            b2sum[ct] += __shfl_xor(b2sum[ct], 32);
        }
        float* red = (float*)&sA[0][0];   // sA dead after the final __syncthreads
        if (quad == 0) {
#pragma unroll
            for (int ct = 0; ct < 4; ++ct) {
                red[wv * 128 + ct * 16 + m]       = bsum[ct];
                red[512 + wv * 128 + ct * 16 + m] = b2sum[ct];
            }
        }
        __syncthreads();
        if (t < 128) {
            int c = t & 63, which = t >> 6;
            float v = red[which * 512 + c] + red[which * 512 + 128 + c] +
                      red[which * 512 + 256 + c] + red[which * 512 + 384 + c];
            atomicAdd(&ACC[which * 256 + GRP * 64 + c], v);
        }
    }
}

extern "C" void kernel_launch(void* const* d_in, const int* in_sizes, int n_in,
                              void* d_out, int out_size, void* d_ws, size_t ws_size,
                              hipStream_t stream) {
    const float* x     = (const float*)d_in[0];
    const int*   neigh = (const int*)d_in[1];
    const float* G[4]  = {(const float*)d_in[2],  (const float*)d_in[6],
                          (const float*)d_in[10], (const float*)d_in[14]};
    const float* B[4]  = {(const float*)d_in[3],  (const float*)d_in[7],
                          (const float*)d_in[11], (const float*)d_in[15]};
    const float* W[4]  = {(const float*)d_in[4],  (const float*)d_in[8],
                          (const float*)d_in[12], (const float*)d_in[16]};
    const float* WB[4] = {(const float*)d_in[5],  (const float*)d_in[9],
                          (const float*)d_in[13], (const float*)d_in[17]};
    float* out = (float*)d_out;

    char* ws = (char*)d_ws;
    size_t off = 0;
    unsigned short* C  = (unsigned short*)(ws + off); off += (size_t)NV * 256 * 2;  // raw concat x|x1|x2|x3 (bf16)
    unsigned short* CN = (unsigned short*)(ws + off); off += (size_t)NV * 256 * 2;  // normalized rows, stride 256
    unsigned short* WT = (unsigned short*)(ws + off); off += (size_t)286720 * 2;    // all 4 transposed W
    float* ACC         = (float*)(ws + off);          off += 512 * 4;               // sum[256], sumsq[256]

    hipMemsetAsync(ACC, 0, 512 * sizeof(float), stream);
    k_cast_wt<<<CAST_BLOCKS + WT_BLOCKS, 256, 0, stream>>>(x, C, ACC,
                                                           W[0], W[1], W[2], W[3], WT);

    const int GG = (NV + 127) / 128;
    const int NB = 2048;   // grid-stride cap for norm passes

    k_norm<1><<<NB, 256, 0, stream>>>(C, ACC, G[0], B[0], G[1], B[1], G[2], B[2], G[3], B[3], CN);
    k_gg< 64, 1, false><<<GG, 256, 0, stream>>>(CN, neigh, WT,          WB[0], ACC, C, nullptr);
    k_norm<2><<<NB, 256, 0, stream>>>(C, ACC, G[0], B[0], G[1], B[1], G[2], B[2], G[3], B[3], CN);
    k_gg<128, 2, false><<<GG, 256, 0, stream>>>(CN, neigh, WT + 28672,  WB[1], ACC, C, nullptr);
    k_norm<3><<<NB, 256, 0, stream>>>(C, ACC, G[0], B[0], G[1], B[1], G[2], B[2], G[3], B[3], CN);
    k_gg<192, 3, false><<<GG, 256, 0, stream>>>(CN, neigh, WT + 86016,  WB[2], ACC, C, nullptr);
    k_norm<4><<<NB, 256, 0, stream>>>(C, ACC, G[0], B[0], G[1], B[1], G[2], B[2], G[3], B[3], CN);
    k_gg<256, 0, true ><<<GG, 256, 0, stream>>>(CN, neigh, WT + 172032, WB[3], ACC, nullptr, out);
}

// Round 7
// 541.019 us; speedup vs baseline: 1.5699x; 1.2502x over previous
//
#include <hip/hip_runtime.h>
#include <stdint.h>

#define NV 163842
#define EPSV 1e-5f

using short8 = __attribute__((ext_vector_type(8))) short;   // 8 bf16 (4 VGPRs)
using f32x4  = __attribute__((ext_vector_type(4))) float;   // MFMA acc

static __device__ __forceinline__ unsigned short f2bf(float f) {
    union { float f; unsigned int i; } v; v.f = f;
    return (unsigned short)((v.i + 0x7FFFu + ((v.i >> 16) & 1u)) >> 16);  // RNE
}
static __device__ __forceinline__ void bf2x(unsigned int w, float& a, float& b) {
    union { unsigned int i; float f; } lo, hi;
    lo.i = w << 16; hi.i = w & 0xFFFF0000u;
    a = lo.f; b = hi.f;
}
// pack two fp32 -> bf16x2 with round-half-up (+0x8000) and v_perm byte select
static __device__ __forceinline__ unsigned int pack2(float a, float b) {
    union { float f; unsigned int i; } ua, ub; ua.f = a; ub.f = b;
    return __builtin_amdgcn_perm(ub.i + 0x8000u, ua.i + 0x8000u, 0x07060302);
}

// direct global->LDS, 16B per lane; LDS dest is wave-uniform base + lane*16
static __device__ __forceinline__ void gl_lds16(const unsigned short* g, unsigned short* l) {
    __builtin_amdgcn_global_load_lds((__attribute__((address_space(1))) void*)g,
                                     (__attribute__((address_space(3))) void*)l, 16, 0, 0);
}

// ---- merged: cast x fp32->bf16 into C cols [0,64) + per-channel stats,
//      and transpose all four W -> WT bf16 (blockIdx branch) ----
#define CAST_BLOCKS 2561   /* (NV+63)/64 */
#define WT_BLOCKS   1120   /* 286720/256 */
__global__ __launch_bounds__(256) void k_cast_wt(const float* __restrict__ x,
                                                 unsigned short* __restrict__ C,
                                                 float* __restrict__ ACC,
                                                 const float* __restrict__ W1,
                                                 const float* __restrict__ W2,
                                                 const float* __restrict__ W3,
                                                 const float* __restrict__ W4,
                                                 unsigned short* __restrict__ WT) {
    const int t = threadIdx.x;
    if (blockIdx.x >= CAST_BLOCKS) {   // ---- W transpose part ----
        int j = (blockIdx.x - CAST_BLOCKS) * 256 + t;
        if (j >= 286720) return;
        const float* W; int jj, K7;
        if (j < 28672)       { W = W1; jj = j;          K7 = 448;  }
        else if (j < 86016)  { W = W2; jj = j - 28672;  K7 = 896;  }
        else if (j < 172032) { W = W3; jj = j - 86016;  K7 = 1344; }
        else                 { W = W4; jj = j - 172032; K7 = 1792; }
        int n = jj / K7, k = jj - n * K7;
        WT[j] = f2bf(W[(size_t)k * 64 + n]);
        return;
    }
    // ---- cast + stats part ----
    const int wv = t >> 6, lane = t & 63;
    const int v = blockIdx.x * 64 + (t >> 2);
    const int c0 = (t & 3) * 16;
    float f[16];
    const bool valid = v < NV;
    if (valid) {
        const float4* p = (const float4*)(x + (size_t)v * 64 + c0);
#pragma unroll
        for (int i = 0; i < 4; ++i) {
            float4 q = p[i];
            f[i * 4 + 0] = q.x; f[i * 4 + 1] = q.y; f[i * 4 + 2] = q.z; f[i * 4 + 3] = q.w;
        }
        unsigned int o[8];
#pragma unroll
        for (int i = 0; i < 8; ++i)
            o[i] = ((unsigned int)f2bf(f[2 * i])) | (((unsigned int)f2bf(f[2 * i + 1])) << 16);
        uint4* dst = (uint4*)(C + (size_t)v * 256 + c0);
        dst[0] = uint4{o[0], o[1], o[2], o[3]};
        dst[1] = uint4{o[4], o[5], o[6], o[7]};
    } else {
#pragma unroll
        for (int i = 0; i < 16; ++i) f[i] = 0.f;
    }
    float s[16], s2[16];
#pragma unroll
    for (int i = 0; i < 16; ++i) { s[i] = f[i]; s2[i] = f[i] * f[i]; }
#pragma unroll
    for (int mask = 4; mask <= 32; mask <<= 1) {
#pragma unroll
        for (int i = 0; i < 16; ++i) {
            s[i]  += __shfl_xor(s[i],  mask);
            s2[i] += __shfl_xor(s2[i], mask);
        }
    }
    __shared__ float red[4 * 128];
    if ((lane >> 2) == 0) {
        int cb = (lane & 3) * 16;
#pragma unroll
        for (int i = 0; i < 16; ++i) {
            red[wv * 128 + cb + i]      = s[i];
            red[wv * 128 + 64 + cb + i] = s2[i];
        }
    }
    __syncthreads();
    if (t < 128) {
        float v4 = red[t] + red[128 + t] + red[256 + t] + red[384 + t];
        int c = t & 63, which = t >> 6;
        atomicAdd(&ACC[which * 256 + c], v4);
    }
}

// ---- per-layer BN+LeakyReLU, applied once per vertex, with DATA-ADAPTIVE group
//      skipping. The param-chain replay compare is LANE-PARALLEL (one channel per
//      lane + __any), replacing round-6's 64-iteration serial dependent-branch
//      chain that made k_norm latency-bound at 131 us. ----
template<int L>   // layer 1..4, CIN = 64*L
__global__ __launch_bounds__(256) void k_norm(const unsigned short* __restrict__ C,
                                              const float* __restrict__ ACC,
                                              const float* __restrict__ G1, const float* __restrict__ B1,
                                              const float* __restrict__ G2, const float* __restrict__ B2,
                                              const float* __restrict__ G3, const float* __restrict__ B3,
                                              const float* __restrict__ G4, const float* __restrict__ B4,
                                              unsigned short* __restrict__ CN) {
    constexpr int CIN = 64 * L;
    __shared__ float ssc[256], ssh[256];
    const int t = threadIdx.x;
    const float* Gs[4] = {G1, G2, G3, G4};
    const float* Bs[4] = {B1, B2, B3, B4};
    if (t < CIN) {
        float s = ACC[t], s2 = ACC[256 + t];
        float mu = s * (1.0f / NV);
        float var = fmaf(-mu, mu, s2 * (1.0f / NV));
        float sc = Gs[L - 1][t] * rsqrtf(var + EPSV);
        ssc[t] = sc;
        ssh[t] = Bs[L - 1][t] - mu * sc;
    }
    __syncthreads();

    // lane-parallel param compare: lane (t&63) checks one channel; __any reduces.
    // Result is identical across all waves/blocks (uniform inputs).
    const int lc = t & 63;
    auto differs = [&](int la, int lb, int g) -> bool {
        int c = g * 64 + lc;
        bool d = (Gs[la][c] != Gs[lb][c]) || (Bs[la][c] != Bs[lb][c]);
        return __any(d);
    };

    for (int g = 0; g < L; ++g) {
        bool need;
        if (g == L - 1) {
            need = true;                      // new group: first normalization
        } else {
            int effL = g;                     // layer whose params the group embodies
            for (int l = g + 1; l <= L - 2; ++l)
                if (differs(l, effL, g)) effL = l;
            need = differs(L - 1, effL, g);
        }
        if (!need) continue;
        const int total = NV * 8;             // 8 x (8-channel uint4 chunks) per row
        for (int idx = blockIdx.x * 256 + t; idx < total; idx += gridDim.x * 256) {
            int v = idx >> 3;
            int ch = g * 64 + (idx & 7) * 8;
            uint4 u = *(const uint4*)(C + (size_t)v * 256 + ch);
            unsigned int in[4] = {u.x, u.y, u.z, u.w}, o[4];
#pragma unroll
            for (int j = 0; j < 4; ++j) {
                float lo, hi; bf2x(in[j], lo, hi);
                float y0 = fmaf(lo, ssc[ch + 2 * j],     ssh[ch + 2 * j]);
                float y1 = fmaf(hi, ssc[ch + 2 * j + 1], ssh[ch + 2 * j + 1]);
                y0 = y0 > 0.f ? y0 : 0.2f * y0;
                y1 = y1 > 0.f ? y1 : 0.2f * y1;
                o[j] = pack2(y0, y1);
            }
            *(uint4*)(CN + (size_t)v * 256 + ch) = uint4{o[0], o[1], o[2], o[3]};
        }
    }
}

// ---- gathered GEMM (round-3 verified structure, at the random-fetch roofline):
//      pure-copy gather via global_load_lds, double-buffered LDS, T3 minimal
//      pipeline: STAGE(next) -> compute(cur) -> __syncthreads -> swap. ----
template<int CIN, int GRP, bool FINAL>
__global__ __launch_bounds__(256) void k_gg(const unsigned short* __restrict__ CN,
                                            const int* __restrict__ neigh,
                                            const unsigned short* __restrict__ WT,
                                            const float* __restrict__ wb,
                                            float* __restrict__ ACC,
                                            unsigned short* __restrict__ Cout,
                                            float* __restrict__ Fout) {
    constexpr int KB = CIN / 64;      // K-chunks per neighbor
    constexpr int NC = 7 * KB;        // total 64-wide K chunks
    constexpr int K7 = 7 * CIN;       // WT row stride (shorts)

    __shared__ int sIdx[896];
    __shared__ unsigned short sA[2][128 * 64];   // double-buffered, linear, 128 B rows
    __shared__ unsigned short sW[2][64 * 64];

    const int t = threadIdx.x;
    const int v0 = blockIdx.x * 128;
    const int wv = t >> 6, lane = t & 63;
    const int m = lane & 15, quad = lane >> 4;
    const int rowin = lane >> 3, slot = lane & 7;
    const int sw = ((slot ^ rowin) * 8);      // swizzled source offset within chunk (shorts)

    for (int q = t; q < 896; q += 256) {
        int gi = v0 * 7 + q;
        sIdx[q] = (gi < NV * 7) ? neigh[gi] : 0;
    }

    f32x4 acc[2][4];
#pragma unroll
    for (int i = 0; i < 2; ++i)
#pragma unroll
        for (int j = 0; j < 4; ++j) acc[i][j] = f32x4{0.f, 0.f, 0.f, 0.f};

    __syncthreads();   // sIdx ready

    auto issue_stage = [&](int r, int kb, int c, int b) {
        // A: 4 issues/wave, 8 rows each; CN rows are stride-256
#pragma unroll
        for (int i = 0; i < 4; ++i) {
            int gidx = sIdx[(wv * 32 + i * 8 + rowin) * 7 + r];
            gl_lds16(CN + (size_t)gidx * 256 + kb * 64 + sw, &sA[b][(wv * 32 + i * 8) * 64]);
        }
        // W: 2 issues/wave
#pragma unroll
        for (int j = 0; j < 2; ++j) {
            int n = wv * 16 + j * 8 + rowin;
            gl_lds16(WT + (size_t)n * K7 + c * 64 + sw, &sW[b][(wv * 16 + j * 8) * 64]);
        }
    };
    auto compute = [&](int b) {
        __builtin_amdgcn_s_setprio(1);
#pragma unroll
        for (int s = 0; s < 2; ++s) {
            const int sx = ((s * 4 + quad) ^ (m & 7)) * 8;   // swizzled frag read (shorts)
            short8 af0 = *(const short8*)(&sA[b][(wv * 32 + m) * 64 + sx]);
            short8 af1 = *(const short8*)(&sA[b][(wv * 32 + 16 + m) * 64 + sx]);
#pragma unroll
            for (int ct = 0; ct < 4; ++ct) {
                short8 bf = *(const short8*)(&sW[b][(ct * 16 + m) * 64 + sx]);
                acc[0][ct] = __builtin_amdgcn_mfma_f32_16x16x32_bf16(af0, bf, acc[0][ct], 0, 0, 0);
                acc[1][ct] = __builtin_amdgcn_mfma_f32_16x16x32_bf16(af1, bf, acc[1][ct], 0, 0, 0);
            }
        }
        __builtin_amdgcn_s_setprio(0);
    };

    issue_stage(0, 0, 0, 0);
    __syncthreads();

    int r = 0, kb = 0, buf = 0;
    for (int c = 0; c < NC - 1; ++c) {
        int kb1 = kb + 1, r1 = r;
        if (kb1 == KB) { kb1 = 0; r1 = r + 1; }
        issue_stage(r1, kb1, c + 1, buf ^ 1);   // in flight across the compute phase
        compute(buf);
        __syncthreads();                        // drains vmcnt(0): chunk c+1 resident; buf reusable
        r = r1; kb = kb1; buf ^= 1;
    }
    compute(buf);
    __syncthreads();   // before reusing sA as reduction scratch

    // epilogue: bias, write raw group, per-channel stats for the produced 64-col group
    float bsum[4]  = {0.f, 0.f, 0.f, 0.f};
    float b2sum[4] = {0.f, 0.f, 0.f, 0.f};
#pragma unroll
    for (int mt = 0; mt < 2; ++mt) {
#pragma unroll
        for (int ct = 0; ct < 4; ++ct) {
            int col = ct * 16 + m;
            float bv = wb[col];
#pragma unroll
            for (int j = 0; j < 4; ++j) {
                int vr = v0 + wv * 32 + mt * 16 + quad * 4 + j;
                float val = acc[mt][ct][j] + bv;
                if (vr < NV) {
                    if (FINAL) {
                        Fout[(size_t)vr * 64 + col] = val;
                    } else {
                        Cout[(size_t)vr * 256 + GRP * 64 + col] = f2bf(val);
                        bsum[ct] += val; b2sum[ct] += val * val;
                    }
                }
            }
        }
    }
    if (!FINAL) {
#pragma unroll
        for (int ct = 0; ct < 4; ++ct) {   // reduce over quads (rows within wave)
            bsum[ct]  += __shfl_xor(bsum[ct], 16);
            bsum[ct]  += __shfl_xor(bsum[ct], 32);
            b2sum[ct] += __shfl_xor(b2sum[ct], 16);
            b2sum[ct] += __shfl_xor(b2sum[ct], 32);
        }
        float* red = (float*)&sA[0][0];   // sA dead after the final __syncthreads
        if (quad == 0) {
#pragma unroll
            for (int ct = 0; ct < 4; ++ct) {
                red[wv * 128 + ct * 16 + m]       = bsum[ct];
                red[512 + wv * 128 + ct * 16 + m] = b2sum[ct];
            }
        }
        __syncthreads();
        if (t < 128) {
            int c = t & 63, which = t >> 6;
            float v = red[which * 512 + c] + red[which * 512 + 128 + c] +
                      red[which * 512 + 256 + c] + red[which * 512 + 384 + c];
            atomicAdd(&ACC[which * 256 + GRP * 64 + c], v);
        }
    }
}

extern "C" void kernel_launch(void* const* d_in, const int* in_sizes, int n_in,
                              void* d_out, int out_size, void* d_ws, size_t ws_size,
                              hipStream_t stream) {
    const float* x     = (const float*)d_in[0];
    const int*   neigh = (const int*)d_in[1];
    const float* G[4]  = {(const float*)d_in[2],  (const float*)d_in[6],
                          (const float*)d_in[10], (const float*)d_in[14]};
    const float* B[4]  = {(const float*)d_in[3],  (const float*)d_in[7],
                          (const float*)d_in[11], (const float*)d_in[15]};
    const float* W[4]  = {(const float*)d_in[4],  (const float*)d_in[8],
                          (const float*)d_in[12], (const float*)d_in[16]};
    const float* WB[4] = {(const float*)d_in[5],  (const float*)d_in[9],
                          (const float*)d_in[13], (const float*)d_in[17]};
    float* out = (float*)d_out;

    char* ws = (char*)d_ws;
    size_t off = 0;
    unsigned short* C  = (unsigned short*)(ws + off); off += (size_t)NV * 256 * 2;  // raw concat x|x1|x2|x3 (bf16)
    unsigned short* CN = (unsigned short*)(ws + off); off += (size_t)NV * 256 * 2;  // normalized rows, stride 256
    unsigned short* WT = (unsigned short*)(ws + off); off += (size_t)286720 * 2;    // all 4 transposed W
    float* ACC         = (float*)(ws + off);          off += 512 * 4;               // sum[256], sumsq[256]

    hipMemsetAsync(ACC, 0, 512 * sizeof(float), stream);
    k_cast_wt<<<CAST_BLOCKS + WT_BLOCKS, 256, 0, stream>>>(x, C, ACC,
                                                           W[0], W[1], W[2], W[3], WT);

    const int GG = (NV + 127) / 128;
    const int NB = 2048;   // grid-stride cap for norm passes

    k_norm<1><<<NB, 256, 0, stream>>>(C, ACC, G[0], B[0], G[1], B[1], G[2], B[2], G[3], B[3], CN);
    k_gg< 64, 1, false><<<GG, 256, 0, stream>>>(CN, neigh, WT,          WB[0], ACC, C, nullptr);
    k_norm<2><<<NB, 256, 0, stream>>>(C, ACC, G[0], B[0], G[1], B[1], G[2], B[2], G[3], B[3], CN);
    k_gg<128, 2, false><<<GG, 256, 0, stream>>>(CN, neigh, WT + 28672,  WB[1], ACC, C, nullptr);
    k_norm<3><<<NB, 256, 0, stream>>>(C, ACC, G[0], B[0], G[1], B[1], G[2], B[2], G[3], B[3], CN);
    k_gg<192, 3, false><<<GG, 256, 0, stream>>>(CN, neigh, WT + 86016,  WB[2], ACC, C, nullptr);
    k_norm<4><<<NB, 256, 0, stream>>>(C, ACC, G[0], B[0], G[1], B[1], G[2], B[2], G[3], B[3], CN);
    k_gg<256, 0, true ><<<GG, 256, 0, stream>>>(CN, neigh, WT + 172032, WB[3], ACC, nullptr, out);
}